// Round 6
// baseline (728.969 us; speedup 1.0000x reference)
//
#include <hip/hip_runtime.h>
#include <cstdint>
#include <cstddef>

#define B_    1024
#define L_    200
#define DIN_  256
#define DOUT_ 256
#define K_    8
#define M_    (B_ * L_)   // 204800

typedef __attribute__((ext_vector_type(8))) short bf16x8;
typedef __attribute__((ext_vector_type(4))) float f32x4;

__device__ __forceinline__ float bf2f(unsigned short u) {
  union { unsigned int i; float f; } w; w.i = ((unsigned int)u) << 16; return w.f;
}
__device__ __forceinline__ unsigned short f2bf(float f) {
  union { float f; unsigned int i; } w; w.f = f;
  unsigned int x = w.i;
  return (unsigned short)((x + 0x7fffu + ((x >> 16) & 1u)) >> 16);
}

// ---------------- kernel 0: split W into bf16 hi/mid/lo in MFMA FRAGMENT ORDER.
// Wfrag[k0b][nt][lane][j]: lane = quad*16+lr encodes (n = nt*16+lr, k = k0b*32+quad*8+j).
__global__ __launch_bounds__(256)
void wt_prep(const float* __restrict__ W, unsigned short* __restrict__ Wh,
             unsigned short* __restrict__ Wm, unsigned short* __restrict__ Wl)
{
  const int k = blockIdx.x;    // 256
  const int n = threadIdx.x;   // 256
  float x = W[k * DOUT_ + n];
  unsigned short h = f2bf(x);
  float r = x - bf2f(h);
  unsigned short m = f2bf(r);
  float r2 = r - bf2f(m);
  unsigned short l = f2bf(r2);
  const int k0b = k >> 5, quad = (k >> 3) & 3, j = k & 7;
  const int nt = n >> 4, lr = n & 15;
  const size_t idx = ((((size_t)k0b * 16 + nt) * 64) + (quad * 16 + lr)) * 8 + j;
  Wh[idx] = h;
  Wm[idx] = m;
  Wl[idx] = l;
}

// ---------------- kernel 1 v3: LDS-staged operands (kills the L2 duplicated-traffic wall).
// Per k0b: B (48 KB, fragment order) staged once per block via coalesced uint4 copy;
// A (16 KB) staged coalesced into padded [128][36] tile. Waves read fragments from LDS.
// MFMA accumulation order per acc is IDENTICAL to R4/R5 -> mapped bit-identical.
#define APAD 36   // row stride 144 B: float4-aligned, 2-way banks at worst (free)

__global__ __launch_bounds__(256, 2)
void gemm_mapped(const float* __restrict__ A,
                 const unsigned short* __restrict__ Wh,
                 const unsigned short* __restrict__ Wm,
                 const unsigned short* __restrict__ Wl,
                 float* __restrict__ C)
{
  const int t    = threadIdx.x;
  const int wave = t >> 6;
  const int lane = t & 63;
  const int quad = lane >> 4;
  const int lr   = lane & 15;
  const int blk0 = blockIdx.x * 128;
  const int m0   = blk0 + wave * 32;

  __shared__ unsigned short Bs[3 * 16 * 64 * 8];  // 48 KB: [split][nt][lane][8]
  __shared__ float As[128][APAD];                 // 18 KB padded fp32 A tile

  f32x4 acc[2][16];
  #pragma unroll
  for (int mt = 0; mt < 2; ++mt)
    #pragma unroll
    for (int nt = 0; nt < 16; ++nt)
      acc[mt][nt] = (f32x4){0.f, 0.f, 0.f, 0.f};

  bf16x8 ah[2], am[2], al[2];

  const uint4* WhU = (const uint4*)Wh;
  const uint4* WmU = (const uint4*)Wm;
  const uint4* WlU = (const uint4*)Wl;
  uint4* BsU = (uint4*)Bs;                        // 3072 uint4: split s at s*1024

  // A staging source: thread t covers row t>>1, 64 B half (t&1)
  const int arow = t >> 1;
  const int acol = (t & 1) * 16;
  const float* abase = A + (size_t)(blk0 + arow) * DIN_ + acol;

  for (int k0b = 0; k0b < 8; ++k0b) {
    // ---- stage B (3 x 1024 uint4, coalesced) + A (coalesced float4)
    #pragma unroll
    for (int i = 0; i < 4; ++i) {
      const int idx = t + i * 256;
      BsU[idx]        = WhU[k0b * 1024 + idx];
      BsU[1024 + idx] = WmU[k0b * 1024 + idx];
      BsU[2048 + idx] = WlU[k0b * 1024 + idx];
    }
    {
      const float* ap = abase + k0b * 32;
      #pragma unroll
      for (int i = 0; i < 4; ++i)
        *(float4*)&As[arow][acol + i * 4] = *(const float4*)(ap + i * 4);
    }
    __syncthreads();

    // ---- A fragments from LDS + bf16x3 split (2-way bank at worst)
    #pragma unroll
    for (int mt = 0; mt < 2; ++mt) {
      const int row = wave * 32 + mt * 16 + lr;
      float4 f0 = *(const float4*)&As[row][quad * 8];
      float4 f1 = *(const float4*)&As[row][quad * 8 + 4];
      float xs[8] = {f0.x, f0.y, f0.z, f0.w, f1.x, f1.y, f1.z, f1.w};
      #pragma unroll
      for (int j = 0; j < 8; ++j) {
        unsigned short h = f2bf(xs[j]);
        float r = xs[j] - bf2f(h);
        unsigned short mm = f2bf(r);
        float r2 = r - bf2f(mm);
        unsigned short ll = f2bf(r2);
        ah[mt][j] = (short)h; am[mt][j] = (short)mm; al[mt][j] = (short)ll;
      }
    }

    // ---- nt loop: B fragments from LDS (lane*16B, conflict-free), 12 MFMAs each
    #pragma unroll
    for (int nt = 0; nt < 16; ++nt) {
      bf16x8 bh = *(const bf16x8*)&Bs[(0 * 16 + nt) * 512 + lane * 8];
      bf16x8 bm = *(const bf16x8*)&Bs[(1 * 16 + nt) * 512 + lane * 8];
      bf16x8 bl = *(const bf16x8*)&Bs[(2 * 16 + nt) * 512 + lane * 8];
      f32x4 c0 = acc[0][nt], c1 = acc[1][nt];
      c0 = __builtin_amdgcn_mfma_f32_16x16x32_bf16(ah[0], bh, c0, 0, 0, 0);
      c1 = __builtin_amdgcn_mfma_f32_16x16x32_bf16(ah[1], bh, c1, 0, 0, 0);
      c0 = __builtin_amdgcn_mfma_f32_16x16x32_bf16(ah[0], bm, c0, 0, 0, 0);
      c1 = __builtin_amdgcn_mfma_f32_16x16x32_bf16(ah[1], bm, c1, 0, 0, 0);
      c0 = __builtin_amdgcn_mfma_f32_16x16x32_bf16(am[0], bh, c0, 0, 0, 0);
      c1 = __builtin_amdgcn_mfma_f32_16x16x32_bf16(am[1], bh, c1, 0, 0, 0);
      c0 = __builtin_amdgcn_mfma_f32_16x16x32_bf16(ah[0], bl, c0, 0, 0, 0);
      c1 = __builtin_amdgcn_mfma_f32_16x16x32_bf16(ah[1], bl, c1, 0, 0, 0);
      c0 = __builtin_amdgcn_mfma_f32_16x16x32_bf16(am[0], bm, c0, 0, 0, 0);
      c1 = __builtin_amdgcn_mfma_f32_16x16x32_bf16(am[1], bm, c1, 0, 0, 0);
      c0 = __builtin_amdgcn_mfma_f32_16x16x32_bf16(al[0], bh, c0, 0, 0, 0);
      c1 = __builtin_amdgcn_mfma_f32_16x16x32_bf16(al[1], bh, c1, 0, 0, 0);
      acc[0][nt] = c0; acc[1][nt] = c1;
    }
    __syncthreads();
  }

  // C/D layout: row = quad*4 + reg, col = lr (within each 16x16 tile)
  #pragma unroll
  for (int mt = 0; mt < 2; ++mt)
    #pragma unroll
    for (int nt = 0; nt < 16; ++nt)
      #pragma unroll
      for (int r = 0; r < 4; ++r) {
        int row = m0 + mt * 16 + quad * 4 + r;
        C[(size_t)row * DOUT_ + nt * 16 + lr] = acc[mt][nt][r];
      }
}

// ---------------- kernel 2: fused masked-softmax + Z + squash (R4 version: wave-per-b)
__global__ __launch_bounds__(256)
void z_kernel(const float* __restrict__ mapped, const float* __restrict__ logits,
              const int* __restrict__ seq_len, float* __restrict__ caps)
{
  const int t    = threadIdx.x;
  const int lane = t & 63;
  const int wave = t >> 6;
  const int b    = blockIdx.x * 4 + wave;
  const int len  = seq_len[b];          // 1..200
  __shared__ float w[4][K_][204];

  #pragma unroll
  for (int k = 0; k < K_; ++k) {
    float v[4];
    float mx = -3.4028235e38f;
    #pragma unroll
    for (int i = 0; i < 4; ++i) {
      int l = lane + 64 * i;
      v[i] = (l < len) ? logits[k * L_ + l] : -3.4028235e38f;
      mx = fmaxf(mx, v[i]);
    }
    #pragma unroll
    for (int s = 1; s < 64; s <<= 1) mx = fmaxf(mx, __shfl_xor(mx, s, 64));
    float e[4]; float sum = 0.f;
    #pragma unroll
    for (int i = 0; i < 4; ++i) {
      int l = lane + 64 * i;
      e[i] = (l < len) ? __expf(v[i] - mx) : 0.f;
      sum += e[i];
    }
    #pragma unroll
    for (int s = 1; s < 64; s <<= 1) sum += __shfl_xor(sum, s, 64);
    float inv = 1.f / sum;
    #pragma unroll
    for (int i = 0; i < 4; ++i) {
      int l = lane + 64 * i;
      if (l < 204) w[wave][k][l] = e[i] * inv;   // exactly 0 for l >= len
    }
  }

  f32x4 acc[K_];
  #pragma unroll
  for (int k = 0; k < K_; ++k) acc[k] = (f32x4){0.f, 0.f, 0.f, 0.f};
  const float* mp = mapped + (size_t)b * L_ * DOUT_ + lane * 4;
  const int lceil = (len + 3) & ~3;
  for (int l = 0; l < lceil; l += 4) {
    float4 m0 = *(const float4*)(mp + (size_t)(l + 0) * DOUT_);
    float4 m1 = *(const float4*)(mp + (size_t)(l + 1) * DOUT_);
    float4 m2 = *(const float4*)(mp + (size_t)(l + 2) * DOUT_);
    float4 m3 = *(const float4*)(mp + (size_t)(l + 3) * DOUT_);
    #pragma unroll
    for (int k = 0; k < K_; ++k) {
      float4 wv = *(const float4*)&w[wave][k][l];
      f32x4 c = acc[k];
      c.x += wv.x * m0.x + wv.y * m1.x + wv.z * m2.x + wv.w * m3.x;
      c.y += wv.x * m0.y + wv.y * m1.y + wv.z * m2.y + wv.w * m3.y;
      c.z += wv.x * m0.z + wv.y * m1.z + wv.z * m2.z + wv.w * m3.z;
      c.w += wv.x * m0.w + wv.y * m1.w + wv.z * m2.w + wv.w * m3.w;
      acc[k] = c;
    }
  }

  #pragma unroll
  for (int k = 0; k < K_; ++k) {
    float sq = acc[k].x * acc[k].x + acc[k].y * acc[k].y
             + acc[k].z * acc[k].z + acc[k].w * acc[k].w;
    #pragma unroll
    for (int s = 1; s < 64; s <<= 1) sq += __shfl_xor(sq, s, 64);
    float scale = sq / ((1.f + sq) * sqrtf(sq + 1e-8f));
    float4 o;
    o.x = scale * acc[k].x; o.y = scale * acc[k].y;
    o.z = scale * acc[k].z; o.w = scale * acc[k].w;
    *(float4*)&caps[((size_t)b * K_ + k) * DOUT_ + lane * 4] = o;
  }
}

// ---------------- kernel 3 v3: block = (lc: 16 l, bc: 16 b); waves in 2x2 (b-half, l-half).
__global__ __launch_bounds__(256)
void delta_kernel(const float* __restrict__ mapped, const float* __restrict__ caps,
                  float* __restrict__ partials)
{
  const int t    = threadIdx.x;
  const int lane = t & 63;
  const int wave = t >> 6;
  const int lc   = blockIdx.x % 13;   // 13 chunks of 16 l (208 >= 200, tail masked)
  const int bc   = blockIdx.x / 13;   // 64 chunks of 16 b
  const int bsub = (wave >> 1) * 8;
  const int lsub = (wave & 1) * 8;
  const int l0   = lc * 16 + lsub;
  const int b0   = bc * 16 + bsub;
  const int o4   = lane * 4;

  float acc[K_][8];
  #pragma unroll
  for (int k = 0; k < K_; ++k)
    #pragma unroll
    for (int ll = 0; ll < 8; ++ll) acc[k][ll] = 0.f;

  for (int bi = 0; bi < 8; ++bi) {
    const int b = b0 + bi;
    const float* cp = caps + (size_t)b * (K_ * DOUT_) + o4;
    const float* mp = mapped + ((size_t)b * L_ + l0) * DOUT_ + o4;
    float4 cv[K_], mv[8];
    #pragma unroll
    for (int k = 0; k < K_; ++k) cv[k] = *(const float4*)(cp + (size_t)k * DOUT_);
    #pragma unroll
    for (int ll = 0; ll < 8; ++ll) {
      mv[ll] = (l0 + ll < L_) ? *(const float4*)(mp + (size_t)ll * DOUT_)
                              : make_float4(0.f, 0.f, 0.f, 0.f);
    }
    #pragma unroll
    for (int k = 0; k < K_; ++k)
      #pragma unroll
      for (int ll = 0; ll < 8; ++ll)
        acc[k][ll] += cv[k].x * mv[ll].x + cv[k].y * mv[ll].y
                    + cv[k].z * mv[ll].z + cv[k].w * mv[ll].w;
  }

  float out = 0.f;
  #pragma unroll
  for (int k = 0; k < K_; ++k)
    #pragma unroll
    for (int ll = 0; ll < 8; ++ll) {
      float v = acc[k][ll];
      v += __shfl_xor(v, 1, 64);
      v += __shfl_xor(v, 2, 64);
      v += __shfl_xor(v, 4, 64);
      v += __shfl_xor(v, 8, 64);
      v += __shfl_xor(v, 16, 64);
      v += __shfl_xor(v, 32, 64);
      if (lane == k * 8 + ll) out = v;
    }
  __shared__ float red[4][64];
  red[wave][lane] = out;
  __syncthreads();
  if (wave < 2) {
    float v = red[wave][lane] + red[wave + 2][lane];
    const int k  = lane >> 3;
    const int ll = lane & 7;
    const int gl = lc * 16 + wave * 8 + ll;
    if (gl < L_) partials[((size_t)bc * K_ + k) * L_ + gl] = v;
  }
}

// ---------------- small kernels
__global__ __launch_bounds__(256)
void init_logits(const float* __restrict__ rlog, float* __restrict__ logits)
{
  int i = blockIdx.x * 256 + threadIdx.x;
  if (i < K_ * L_) logits[i] = rlog[i];
}

__global__ __launch_bounds__(256)
void reduce_kernel(const float* __restrict__ partials, float* __restrict__ logits)
{
  int i = blockIdx.x * 256 + threadIdx.x;
  if (i < K_ * L_) {
    float s = 0.f;
    #pragma unroll 4
    for (int bc = 0; bc < 64; ++bc) s += partials[bc * (K_ * L_) + i];
    logits[i] += s;
  }
}

extern "C" void kernel_launch(void* const* d_in, const int* in_sizes, int n_in,
                              void* d_out, int out_size, void* d_ws, size_t ws_size,
                              hipStream_t stream)
{
  const float* behav = (const float*)d_in[0];
  const int*   slen  = (const int*)d_in[1];
  const float* rlog  = (const float*)d_in[2];
  const float* W     = (const float*)d_in[3];
  float* caps = (float*)d_out;

  char* ws = (char*)d_ws;
  float* logitsW  = (float*)ws;                           // 6400 B
  float* partials = (float*)(ws + 8192);                  // 409600 B (ends 417792)
  unsigned short* Wh = (unsigned short*)(ws + 458752);    // 128 KiB each
  unsigned short* Wm = (unsigned short*)(ws + 589824);
  unsigned short* Wl = (unsigned short*)(ws + 720896);    // ends 851968 < 1 MiB
  float* mapped   = (float*)(ws + (1 << 20));             // 200 MiB fp32

  init_logits<<<dim3(7), 256, 0, stream>>>(rlog, logitsW);
  wt_prep<<<dim3(256), 256, 0, stream>>>(W, Wh, Wm, Wl);
  gemm_mapped<<<dim3(1600), 256, 0, stream>>>(behav, Wh, Wm, Wl, mapped);
  for (int it = 0; it < 3; ++it) {
    z_kernel<<<dim3(B_ / 4), 256, 0, stream>>>(mapped, logitsW, slen, caps);
    if (it < 2) {   // delta after the last iteration is dead code in the reference
      delta_kernel<<<dim3(13 * 64), 256, 0, stream>>>(mapped, caps, partials);
      reduce_kernel<<<dim3(7), 256, 0, stream>>>(partials, logitsW);
    }
  }
}

// Round 7
// 678.551 us; speedup vs baseline: 1.0743x; 1.0743x over previous
//
#include <hip/hip_runtime.h>
#include <cstdint>
#include <cstddef>

#define B_    1024
#define L_    200
#define DIN_  256
#define DOUT_ 256
#define K_    8
#define M_    (B_ * L_)   // 204800

typedef __attribute__((ext_vector_type(8))) short bf16x8;
typedef __attribute__((ext_vector_type(4))) float f32x4;

__device__ __forceinline__ float bf2f(unsigned short u) {
  union { unsigned int i; float f; } w; w.i = ((unsigned int)u) << 16; return w.f;
}
__device__ __forceinline__ unsigned short f2bf(float f) {
  union { float f; unsigned int i; } w; w.f = f;
  unsigned int x = w.i;
  return (unsigned short)((x + 0x7fffu + ((x >> 16) & 1u)) >> 16);
}

// async global->LDS 16B: LDS dest = uniform base + lane*16 (HW-applied)
__device__ __forceinline__ void gload_lds16(const unsigned short* g, unsigned short* l) {
  __builtin_amdgcn_global_load_lds(
      (const __attribute__((address_space(1))) void*)g,
      (__attribute__((address_space(3))) void*)l, 16, 0, 0);
}

// ---------------- kernel 0: split W into bf16 hi/mid/lo, single fragment-ordered array.
// Wall[((k0b*3 + split)*16 + ntg)*512 + lane*8 + j], lane=quad*16+lr encodes
// (n = ntg*16+lr, k = k0b*32+quad*8+j). Also folds logits init (saves a dispatch).
__global__ __launch_bounds__(256)
void wt_prep(const float* __restrict__ W, const float* __restrict__ rlog,
             unsigned short* __restrict__ Wall, float* __restrict__ logitsW)
{
  const int k = blockIdx.x;    // 256
  const int n = threadIdx.x;   // 256
  const int gi = blockIdx.x * 256 + threadIdx.x;
  if (gi < K_ * L_) logitsW[gi] = rlog[gi];

  float x = W[k * DOUT_ + n];
  unsigned short h = f2bf(x);
  float r = x - bf2f(h);
  unsigned short m = f2bf(r);
  float r2 = r - bf2f(m);
  unsigned short l = f2bf(r2);
  const int k0b = k >> 5, quad = (k >> 3) & 3, j = k & 7;
  const int ntg = n >> 4, lr = n & 15;
  const int lane = quad * 16 + lr;
  Wall[(((size_t)k0b * 3 + 0) * 16 + ntg) * 512 + lane * 8 + j] = h;
  Wall[(((size_t)k0b * 3 + 1) * 16 + ntg) * 512 + lane * 8 + j] = m;
  Wall[(((size_t)k0b * 3 + 2) * 16 + ntg) * 512 + lane * 8 + j] = l;
}

// ---------------- kernel 1 v4: 128x128 block (nt=8), B double-buffered via async
// global_load_lds; A register-direct (R4 pattern). 3 blocks/CU. MFMA order per acc
// IDENTICAL to R4/R5/R6 -> mapped bit-identical (absmax canary: 0.0009765625).
__global__ __launch_bounds__(256, 3)
void gemm_mapped(const float* __restrict__ A,
                 const unsigned short* __restrict__ Wall,
                 float* __restrict__ C)
{
  const int t    = threadIdx.x;
  const int wave = t >> 6;
  const int lane = t & 63;
  const int quad = lane >> 4;
  const int lr   = lane & 15;
  const int m0   = blockIdx.x * 128 + wave * 32;
  const int nt0  = blockIdx.y * 8;           // 8 n-tiles = 128 cols per block

  __shared__ unsigned short Bs[2][24 * 512]; // 2 x 24 KB: [buf][(s*8+ntl)*512 + lane*8]

  f32x4 acc[2][8];
  #pragma unroll
  for (int mt = 0; mt < 2; ++mt)
    #pragma unroll
    for (int nt = 0; nt < 8; ++nt)
      acc[mt][nt] = (f32x4){0.f, 0.f, 0.f, 0.f};

  bf16x8 ah[2], am[2], al[2];
  float4 Af[2][2];

  // wave stages chunks [wave*6, wave*6+6): chunk c -> split s=c>>3, ntl=c&7
#define STAGE(K0B, BUF) do { \
    _Pragma("unroll") \
    for (int _i = 0; _i < 6; ++_i) { \
      const int _c   = wave * 6 + _i; \
      const int _s   = _c >> 3; \
      const int _ntl = _c & 7; \
      const unsigned short* _g = Wall + \
          ((((size_t)(K0B) * 3 + _s) * 16 + nt0 + _ntl) * 512) + lane * 8; \
      gload_lds16(_g, &Bs[BUF][_c * 512]); \
    } \
  } while (0)

  const float* ap0 = A + (size_t)(m0 + lr) * DIN_ + quad * 8;
  const float* ap1 = A + (size_t)(m0 + 16 + lr) * DIN_ + quad * 8;

  // prologue: async-stage k0b=0 into buf0; A raw loads for k0b=0
  STAGE(0, 0);
  Af[0][0] = *(const float4*)(ap0);
  Af[0][1] = *(const float4*)(ap0 + 4);
  Af[1][0] = *(const float4*)(ap1);
  Af[1][1] = *(const float4*)(ap1 + 4);
  __syncthreads();   // drains vmcnt -> buf0 + Af ready

  for (int k0b = 0; k0b < 8; ++k0b) {
    const int cur = k0b & 1;
    // issue next tile's async stage FIRST -> overlap window = whole body
    if (k0b < 7) STAGE(k0b + 1, cur ^ 1);

    // convert this k0b's A (prefetched last iteration) to bf16x3 fragments
    #pragma unroll
    for (int mt = 0; mt < 2; ++mt) {
      float xs[8] = {Af[mt][0].x, Af[mt][0].y, Af[mt][0].z, Af[mt][0].w,
                     Af[mt][1].x, Af[mt][1].y, Af[mt][1].z, Af[mt][1].w};
      #pragma unroll
      for (int j = 0; j < 8; ++j) {
        unsigned short h = f2bf(xs[j]);
        float r = xs[j] - bf2f(h);
        unsigned short mm = f2bf(r);
        float r2 = r - bf2f(mm);
        unsigned short ll = f2bf(r2);
        ah[mt][j] = (short)h; am[mt][j] = (short)mm; al[mt][j] = (short)ll;
      }
    }
    // issue next k0b's A raw loads (consumed next iteration)
    if (k0b < 7) {
      const int ko = (k0b + 1) * 32;
      Af[0][0] = *(const float4*)(ap0 + ko);
      Af[0][1] = *(const float4*)(ap0 + ko + 4);
      Af[1][0] = *(const float4*)(ap1 + ko);
      Af[1][1] = *(const float4*)(ap1 + ko + 4);
    }

#define GROUP(NT) do { \
    bf16x8 bh = *(const bf16x8*)&Bs[cur][(0 * 8 + (NT)) * 512 + lane * 8]; \
    bf16x8 bm = *(const bf16x8*)&Bs[cur][(1 * 8 + (NT)) * 512 + lane * 8]; \
    bf16x8 bl = *(const bf16x8*)&Bs[cur][(2 * 8 + (NT)) * 512 + lane * 8]; \
    f32x4 c0 = acc[0][NT], c1 = acc[1][NT]; \
    c0 = __builtin_amdgcn_mfma_f32_16x16x32_bf16(ah[0], bh, c0, 0, 0, 0); \
    c1 = __builtin_amdgcn_mfma_f32_16x16x32_bf16(ah[1], bh, c1, 0, 0, 0); \
    c0 = __builtin_amdgcn_mfma_f32_16x16x32_bf16(ah[0], bm, c0, 0, 0, 0); \
    c1 = __builtin_amdgcn_mfma_f32_16x16x32_bf16(ah[1], bm, c1, 0, 0, 0); \
    c0 = __builtin_amdgcn_mfma_f32_16x16x32_bf16(am[0], bh, c0, 0, 0, 0); \
    c1 = __builtin_amdgcn_mfma_f32_16x16x32_bf16(am[1], bh, c1, 0, 0, 0); \
    c0 = __builtin_amdgcn_mfma_f32_16x16x32_bf16(ah[0], bl, c0, 0, 0, 0); \
    c1 = __builtin_amdgcn_mfma_f32_16x16x32_bf16(ah[1], bl, c1, 0, 0, 0); \
    c0 = __builtin_amdgcn_mfma_f32_16x16x32_bf16(am[0], bm, c0, 0, 0, 0); \
    c1 = __builtin_amdgcn_mfma_f32_16x16x32_bf16(am[1], bm, c1, 0, 0, 0); \
    c0 = __builtin_amdgcn_mfma_f32_16x16x32_bf16(al[0], bh, c0, 0, 0, 0); \
    c1 = __builtin_amdgcn_mfma_f32_16x16x32_bf16(al[1], bh, c1, 0, 0, 0); \
    acc[0][NT] = c0; acc[1][NT] = c1; \
  } while (0)

    GROUP(0); GROUP(1); GROUP(2); GROUP(3);
    GROUP(4); GROUP(5); GROUP(6); GROUP(7);
#undef GROUP

    __syncthreads();   // drains this body's async stage; flips buffer
  }
#undef STAGE

  // C/D layout: row = quad*4 + reg, col = lr (within each 16x16 tile)
  #pragma unroll
  for (int mt = 0; mt < 2; ++mt)
    #pragma unroll
    for (int nt = 0; nt < 8; ++nt)
      #pragma unroll
      for (int r = 0; r < 4; ++r) {
        int row = m0 + mt * 16 + quad * 4 + r;
        C[(size_t)row * DOUT_ + (nt0 + nt) * 16 + lr] = acc[mt][nt][r];
      }
}

// ---------------- kernel 2: fused masked-softmax + Z + squash (wave-per-b, unchanged)
__global__ __launch_bounds__(256)
void z_kernel(const float* __restrict__ mapped, const float* __restrict__ logits,
              const int* __restrict__ seq_len, float* __restrict__ caps)
{
  const int t    = threadIdx.x;
  const int lane = t & 63;
  const int wave = t >> 6;
  const int b    = blockIdx.x * 4 + wave;
  const int len  = seq_len[b];          // 1..200
  __shared__ float w[4][K_][204];

  #pragma unroll
  for (int k = 0; k < K_; ++k) {
    float v[4];
    float mx = -3.4028235e38f;
    #pragma unroll
    for (int i = 0; i < 4; ++i) {
      int l = lane + 64 * i;
      v[i] = (l < len) ? logits[k * L_ + l] : -3.4028235e38f;
      mx = fmaxf(mx, v[i]);
    }
    #pragma unroll
    for (int s = 1; s < 64; s <<= 1) mx = fmaxf(mx, __shfl_xor(mx, s, 64));
    float e[4]; float sum = 0.f;
    #pragma unroll
    for (int i = 0; i < 4; ++i) {
      int l = lane + 64 * i;
      e[i] = (l < len) ? __expf(v[i] - mx) : 0.f;
      sum += e[i];
    }
    #pragma unroll
    for (int s = 1; s < 64; s <<= 1) sum += __shfl_xor(sum, s, 64);
    float inv = 1.f / sum;
    #pragma unroll
    for (int i = 0; i < 4; ++i) {
      int l = lane + 64 * i;
      if (l < 204) w[wave][k][l] = e[i] * inv;   // exactly 0 for l >= len
    }
  }

  f32x4 acc[K_];
  #pragma unroll
  for (int k = 0; k < K_; ++k) acc[k] = (f32x4){0.f, 0.f, 0.f, 0.f};
  const float* mp = mapped + (size_t)b * L_ * DOUT_ + lane * 4;
  const int lceil = (len + 3) & ~3;
  for (int l = 0; l < lceil; l += 4) {
    float4 m0 = *(const float4*)(mp + (size_t)(l + 0) * DOUT_);
    float4 m1 = *(const float4*)(mp + (size_t)(l + 1) * DOUT_);
    float4 m2 = *(const float4*)(mp + (size_t)(l + 2) * DOUT_);
    float4 m3 = *(const float4*)(mp + (size_t)(l + 3) * DOUT_);
    #pragma unroll
    for (int k = 0; k < K_; ++k) {
      float4 wv = *(const float4*)&w[wave][k][l];
      f32x4 c = acc[k];
      c.x += wv.x * m0.x + wv.y * m1.x + wv.z * m2.x + wv.w * m3.x;
      c.y += wv.x * m0.y + wv.y * m1.y + wv.z * m2.y + wv.w * m3.y;
      c.z += wv.x * m0.z + wv.y * m1.z + wv.z * m2.z + wv.w * m3.z;
      c.w += wv.x * m0.w + wv.y * m1.w + wv.z * m2.w + wv.w * m3.w;
      acc[k] = c;
    }
  }

  #pragma unroll
  for (int k = 0; k < K_; ++k) {
    float sq = acc[k].x * acc[k].x + acc[k].y * acc[k].y
             + acc[k].z * acc[k].z + acc[k].w * acc[k].w;
    #pragma unroll
    for (int s = 1; s < 64; s <<= 1) sq += __shfl_xor(sq, s, 64);
    float scale = sq / ((1.f + sq) * sqrtf(sq + 1e-8f));
    float4 o;
    o.x = scale * acc[k].x; o.y = scale * acc[k].y;
    o.z = scale * acc[k].z; o.w = scale * acc[k].w;
    *(float4*)&caps[((size_t)b * K_ + k) * DOUT_ + lane * 4] = o;
  }
}

// ---------------- kernel 3: delta partials (unchanged)
__global__ __launch_bounds__(256)
void delta_kernel(const float* __restrict__ mapped, const float* __restrict__ caps,
                  float* __restrict__ partials)
{
  const int t    = threadIdx.x;
  const int lane = t & 63;
  const int wave = t >> 6;
  const int lc   = blockIdx.x % 13;
  const int bc   = blockIdx.x / 13;
  const int bsub = (wave >> 1) * 8;
  const int lsub = (wave & 1) * 8;
  const int l0   = lc * 16 + lsub;
  const int b0   = bc * 16 + bsub;
  const int o4   = lane * 4;

  float acc[K_][8];
  #pragma unroll
  for (int k = 0; k < K_; ++k)
    #pragma unroll
    for (int ll = 0; ll < 8; ++ll) acc[k][ll] = 0.f;

  for (int bi = 0; bi < 8; ++bi) {
    const int b = b0 + bi;
    const float* cp = caps + (size_t)b * (K_ * DOUT_) + o4;
    const float* mp = mapped + ((size_t)b * L_ + l0) * DOUT_ + o4;
    float4 cv[K_], mv[8];
    #pragma unroll
    for (int k = 0; k < K_; ++k) cv[k] = *(const float4*)(cp + (size_t)k * DOUT_);
    #pragma unroll
    for (int ll = 0; ll < 8; ++ll) {
      mv[ll] = (l0 + ll < L_) ? *(const float4*)(mp + (size_t)ll * DOUT_)
                              : make_float4(0.f, 0.f, 0.f, 0.f);
    }
    #pragma unroll
    for (int k = 0; k < K_; ++k)
      #pragma unroll
      for (int ll = 0; ll < 8; ++ll)
        acc[k][ll] += cv[k].x * mv[ll].x + cv[k].y * mv[ll].y
                    + cv[k].z * mv[ll].z + cv[k].w * mv[ll].w;
  }

  float out = 0.f;
  #pragma unroll
  for (int k = 0; k < K_; ++k)
    #pragma unroll
    for (int ll = 0; ll < 8; ++ll) {
      float v = acc[k][ll];
      v += __shfl_xor(v, 1, 64);
      v += __shfl_xor(v, 2, 64);
      v += __shfl_xor(v, 4, 64);
      v += __shfl_xor(v, 8, 64);
      v += __shfl_xor(v, 16, 64);
      v += __shfl_xor(v, 32, 64);
      if (lane == k * 8 + ll) out = v;
    }
  __shared__ float red[4][64];
  red[wave][lane] = out;
  __syncthreads();
  if (wave < 2) {
    float v = red[wave][lane] + red[wave + 2][lane];
    const int k  = lane >> 3;
    const int ll = lane & 7;
    const int gl = lc * 16 + wave * 8 + ll;
    if (gl < L_) partials[((size_t)bc * K_ + k) * L_ + gl] = v;
  }
}

__global__ __launch_bounds__(256)
void reduce_kernel(const float* __restrict__ partials, float* __restrict__ logits)
{
  int i = blockIdx.x * 256 + threadIdx.x;
  if (i < K_ * L_) {
    float s = 0.f;
    #pragma unroll 4
    for (int bc = 0; bc < 64; ++bc) s += partials[bc * (K_ * L_) + i];
    logits[i] += s;
  }
}

extern "C" void kernel_launch(void* const* d_in, const int* in_sizes, int n_in,
                              void* d_out, int out_size, void* d_ws, size_t ws_size,
                              hipStream_t stream)
{
  const float* behav = (const float*)d_in[0];
  const int*   slen  = (const int*)d_in[1];
  const float* rlog  = (const float*)d_in[2];
  const float* W     = (const float*)d_in[3];
  float* caps = (float*)d_out;

  char* ws = (char*)d_ws;
  float* logitsW  = (float*)ws;                           // 6400 B
  float* partials = (float*)(ws + 8192);                  // 409600 B (ends 417792)
  unsigned short* Wall = (unsigned short*)(ws + 458752);  // 384 KiB (ends 851968)
  float* mapped   = (float*)(ws + (1 << 20));             // 200 MiB fp32

  wt_prep<<<dim3(256), 256, 0, stream>>>(W, rlog, Wall, logitsW);
  gemm_mapped<<<dim3(1600, 2), 256, 0, stream>>>(behav, Wall, mapped);
  for (int it = 0; it < 3; ++it) {
    z_kernel<<<dim3(B_ / 4), 256, 0, stream>>>(mapped, logitsW, slen, caps);
    if (it < 2) {   // delta after the last iteration is dead code in the reference
      delta_kernel<<<dim3(13 * 64), 256, 0, stream>>>(mapped, caps, partials);
      reduce_kernel<<<dim3(7), 256, 0, stream>>>(partials, logitsW);
    }
  }
}